// Round 1
// baseline (446.081 us; speedup 1.0000x reference)
//
#include <hip/hip_runtime.h>
#include <math.h>

// Problem constants (fixed by the reference)
#define SPATIAL (64*64*64)   // 262144 elements per (b, channel)
#define SPATIAL4 (SPATIAL/4) // 65536 float4 per channel
#define NCH 64
#define NB 2
#define BN_EPS 1e-5f

// -------- Kernel 1: per-(tensor,b,channel) mean over 64^3 spatial ----------
// 256 blocks: 0..127 -> g channels, 128..255 -> x channels. 512 threads each.
__global__ __launch_bounds__(512) void mean_kernel(const float* __restrict__ g,
                                                   const float* __restrict__ x,
                                                   float* __restrict__ pooled) {
    int blk = blockIdx.x;
    int tid = threadIdx.x;
    const float* src;
    int outIdx;
    if (blk < 128) {
        int b = blk >> 6, c = blk & 63;
        src = g + (size_t)(b * NCH + c) * SPATIAL;
        outIdx = b * 128 + c;              // pooled = [mean(g) | mean(x)] per batch
    } else {
        int id = blk - 128;
        int b = id >> 6, c = id & 63;
        src = x + (size_t)(b * NCH + c) * SPATIAL;
        outIdx = b * 128 + 64 + c;
    }
    const float4* s4 = (const float4*)src;
    float sum = 0.f;
    #pragma unroll 8
    for (int i = tid; i < SPATIAL4; i += 512) {
        float4 v = s4[i];
        sum += (v.x + v.y) + (v.z + v.w);
    }
    // wave reduce (wave = 64 lanes)
    #pragma unroll
    for (int off = 32; off > 0; off >>= 1)
        sum += __shfl_down(sum, off, 64);
    __shared__ float wsum[8];
    int lane = tid & 63, wave = tid >> 6;
    if (lane == 0) wsum[wave] = sum;
    __syncthreads();
    if (tid == 0) {
        float t = 0.f;
        #pragma unroll
        for (int w = 0; w < 8; ++w) t += wsum[w];
        pooled[outIdx] = t * (1.0f / SPATIAL);
    }
}

// -------- Kernel 2: tiny gating MLP + fold psi_w/BN into 128 coefs ---------
// 1 block, 128 threads. coef[0..127] = c[b][g]*bn_scale, coef[128] = bias.
__global__ void mlp_kernel(const float* __restrict__ pooled,
                           const float* __restrict__ w1, const float* __restrict__ b1,
                           const float* __restrict__ w2, const float* __restrict__ b2,
                           const float* __restrict__ psi_w, const float* __restrict__ psi_b,
                           const float* __restrict__ bn_gamma, const float* __restrict__ bn_beta,
                           const float* __restrict__ bn_mean, const float* __restrict__ bn_var,
                           float* __restrict__ coef) {
    __shared__ float p[256];     // pooled [2][128]
    __shared__ float h[2][32];   // hidden
    int tid = threadIdx.x;       // 0..127
    p[tid] = pooled[tid];
    p[tid + 128] = pooled[tid + 128];
    __syncthreads();
    if (tid < 64) {
        int b = tid >> 5, j = tid & 31;
        float acc = b1[j];
        #pragma unroll 8
        for (int k = 0; k < 128; ++k) acc += p[b * 128 + k] * w1[j * 128 + k];
        h[b][j] = fmaxf(acc, 0.f);   // relu
    }
    __syncthreads();
    float scale = bn_gamma[0] * rsqrtf(bn_var[0] + BN_EPS);
    {
        int b = tid >> 6, gc = tid & 63;
        float acc = 0.f;
        for (int l = 0; l < 64; ++l) {
            const float* wrow = w2 + (size_t)(gc * 64 + l) * 32;
            float z = b2[gc * 64 + l];
            #pragma unroll 8
            for (int j = 0; j < 32; ++j) z += h[b][j] * wrow[j];
            float sig = 1.f / (1.f + expf(-z));   // dw[b,gc,l]
            acc += sig * psi_w[l];
        }
        coef[tid] = acc * scale;                  // fold BN scale into coef
    }
    if (tid == 0) coef[128] = (psi_b[0] - bn_mean[0]) * scale + bn_beta[0];
}

// -------- Kernel 3: s = sum_g g*c ; out = x * sigmoid(s + bias) ------------
// 512 blocks x 256 threads; each thread owns exactly one float4 position.
__global__ __launch_bounds__(256) void apply_kernel(const float* __restrict__ g,
                                                    const float* __restrict__ x,
                                                    const float* __restrict__ coef,
                                                    float* __restrict__ out) {
    int blk = blockIdx.x;
    int batch = blk >> 8;                           // 256 blocks per batch
    int pos4 = (blk & 255) * 256 + threadIdx.x;     // float4 index within channel
    size_t batchOff = (size_t)batch * NCH * SPATIAL4;   // in float4 units

    const float4* g4 = (const float4*)g;
    const float4* x4 = (const float4*)x;
    float4* o4 = (float4*)out;

    float4 acc = make_float4(0.f, 0.f, 0.f, 0.f);
    #pragma unroll 16
    for (int gc = 0; gc < NCH; ++gc) {
        float cc = coef[batch * NCH + gc];          // uniform -> scalar load
        float4 v = g4[batchOff + (size_t)gc * SPATIAL4 + pos4];
        acc.x += v.x * cc; acc.y += v.y * cc;
        acc.z += v.z * cc; acc.w += v.w * cc;
    }
    float d = coef[128];
    float4 sig;
    sig.x = 1.f / (1.f + expf(-(acc.x + d)));
    sig.y = 1.f / (1.f + expf(-(acc.y + d)));
    sig.z = 1.f / (1.f + expf(-(acc.z + d)));
    sig.w = 1.f / (1.f + expf(-(acc.w + d)));

    #pragma unroll 8
    for (int l = 0; l < NCH; ++l) {
        size_t idx = batchOff + (size_t)l * SPATIAL4 + pos4;
        float4 xv = x4[idx];
        float4 ov = make_float4(xv.x * sig.x, xv.y * sig.y, xv.z * sig.z, xv.w * sig.w);
        o4[idx] = ov;
    }
}

extern "C" void kernel_launch(void* const* d_in, const int* in_sizes, int n_in,
                              void* d_out, int out_size, void* d_ws, size_t ws_size,
                              hipStream_t stream) {
    const float* g        = (const float*)d_in[0];
    const float* x        = (const float*)d_in[1];
    const float* w1       = (const float*)d_in[2];
    const float* b1       = (const float*)d_in[3];
    const float* w2       = (const float*)d_in[4];
    const float* b2       = (const float*)d_in[5];
    const float* psi_w    = (const float*)d_in[6];
    const float* psi_b    = (const float*)d_in[7];
    const float* bn_gamma = (const float*)d_in[8];
    const float* bn_beta  = (const float*)d_in[9];
    const float* bn_mean  = (const float*)d_in[10];
    const float* bn_var   = (const float*)d_in[11];
    float* out = (float*)d_out;
    float* ws  = (float*)d_ws;

    float* pooled = ws;        // 256 floats
    float* coef   = ws + 256;  // 129 floats

    mean_kernel<<<256, 512, 0, stream>>>(g, x, pooled);
    mlp_kernel<<<1, 128, 0, stream>>>(pooled, w1, b1, w2, b2, psi_w, psi_b,
                                      bn_gamma, bn_beta, bn_mean, bn_var, coef);
    apply_kernel<<<512, 256, 0, stream>>>(g, x, coef, out);
}

// Round 2
// 387.068 us; speedup vs baseline: 1.1525x; 1.1525x over previous
//
#include <hip/hip_runtime.h>
#include <math.h>

// Problem constants (fixed by the reference)
#define SPATIAL (64*64*64)   // 262144 elements per (b, channel)
#define SPATIAL4 (SPATIAL/4) // 65536 float4 per channel
#define QUART4  (SPATIAL4/4) // 16384 float4 per quarter-channel
#define NCH 64
#define NB 2
#define BN_EPS 1e-5f

// -------- Kernel 1: partial sums, 4 blocks per (tensor,b,channel) ----------
// 1024 blocks x 256 threads (16 waves/CU). partial[blk] = sum of its quarter.
__global__ __launch_bounds__(256) void mean_kernel(const float* __restrict__ g,
                                                   const float* __restrict__ x,
                                                   float* __restrict__ partial) {
    int blk = blockIdx.x;          // 0..1023
    int ch  = blk >> 2;            // 0..255 (0..127 = g channels, 128..255 = x)
    int q   = blk & 3;
    const float* src = (ch < 128)
        ? g + (size_t)ch * SPATIAL
        : x + (size_t)(ch - 128) * SPATIAL;
    const float4* s4 = (const float4*)src + (size_t)q * QUART4;

    float sum = 0.f;
    #pragma unroll 8
    for (int i = threadIdx.x; i < QUART4; i += 256) {
        float4 v = s4[i];
        sum += (v.x + v.y) + (v.z + v.w);
    }
    // wave reduce (wave = 64)
    #pragma unroll
    for (int off = 32; off > 0; off >>= 1)
        sum += __shfl_down(sum, off, 64);
    __shared__ float wsum[4];
    int lane = threadIdx.x & 63, wave = threadIdx.x >> 6;
    if (lane == 0) wsum[wave] = sum;
    __syncthreads();
    if (threadIdx.x == 0)
        partial[blk] = wsum[0] + wsum[1] + wsum[2] + wsum[3];
}

// -------- Kernel 2: fold partials -> pooled, gating MLP -> 128 coefs -------
// 128 blocks (one per (b,gc)) x 64 threads (one per l). Coalesced w2 reads.
__global__ __launch_bounds__(64) void mlp_kernel(const float* __restrict__ partial,
                           const float* __restrict__ w1, const float* __restrict__ b1,
                           const float* __restrict__ w2, const float* __restrict__ b2,
                           const float* __restrict__ psi_w, const float* __restrict__ psi_b,
                           const float* __restrict__ bn_gamma, const float* __restrict__ bn_beta,
                           const float* __restrict__ bn_mean, const float* __restrict__ bn_var,
                           float* __restrict__ coef) {
    __shared__ float p[256];   // pooled, layout [b*128 + feature]
    __shared__ float h[32];    // hidden for this block's batch
    int tid = threadIdx.x;     // 0..63
    int blk = blockIdx.x;      // 0..127
    int b = blk >> 6, gc = blk & 63;

    // pooled: sum 4 partials per channel
    #pragma unroll
    for (int ch = tid; ch < 256; ch += 64) {
        float s = partial[4*ch] + partial[4*ch+1] + partial[4*ch+2] + partial[4*ch+3];
        int pi = (ch < 128) ? ((ch >> 6) * 128 + (ch & 63))
                            : (((ch - 128) >> 6) * 128 + 64 + ((ch - 128) & 63));
        p[pi] = s * (1.0f / SPATIAL);
    }
    __syncthreads();
    // hidden layer (redundant per block, cheap): threads 0..31
    if (tid < 32) {
        float acc = b1[tid];
        const float* wr = w1 + tid * 128;
        #pragma unroll 4
        for (int k = 0; k < 128; ++k) acc += p[b * 128 + k] * wr[k];
        h[tid] = fmaxf(acc, 0.f);
    }
    __syncthreads();
    // each thread: one l. w2 row contiguous 128B per lane, block reads 8KB.
    const float4* wr = (const float4*)(w2 + (size_t)(gc * 64 + tid) * 32);
    float z = b2[gc * 64 + tid];
    #pragma unroll
    for (int j = 0; j < 8; ++j) {
        float4 wv = wr[j];
        z += h[4*j] * wv.x + h[4*j+1] * wv.y + h[4*j+2] * wv.z + h[4*j+3] * wv.w;
    }
    float sig = 1.f / (1.f + expf(-z));   // dw[b,gc,l]
    float val = sig * psi_w[tid];
    #pragma unroll
    for (int off = 32; off > 0; off >>= 1)
        val += __shfl_down(val, off, 64);
    float scale = bn_gamma[0] * rsqrtf(bn_var[0] + BN_EPS);
    if (tid == 0) coef[b * 64 + gc] = val * scale;
    if (blk == 0 && tid == 0)
        coef[128] = (psi_b[0] - bn_mean[0]) * scale + bn_beta[0];
}

// -------- Kernel 3: s = sum_g g*c ; out = x * sigmoid(s + bias) ------------
// 1024 blocks x 256 threads. Each block owns 128 float4 positions; two
// thread-halves each reduce 32 g-channels, combine via LDS, then each half
// writes 32 x-channels. 16 waves/CU.
__global__ __launch_bounds__(256) void apply_kernel(const float* __restrict__ g,
                                                    const float* __restrict__ x,
                                                    const float* __restrict__ coef,
                                                    float* __restrict__ out) {
    int t    = threadIdx.x;
    int pos  = t & 127;
    int half = t >> 7;
    int blk  = blockIdx.x;                    // 0..1023
    int batch = blk >> 9;                     // 512 blocks per batch
    int base4 = (blk & 511) * 128 + pos;      // float4 index within channel
    size_t bOff = (size_t)batch * NCH * SPATIAL4;

    const float4* g4 = (const float4*)g;
    const float4* x4 = (const float4*)x;
    float4* o4 = (float4*)out;

    const float* cf = coef + batch * NCH + half * 32;
    float4 acc = make_float4(0.f, 0.f, 0.f, 0.f);
    #pragma unroll 8
    for (int gc = 0; gc < 32; ++gc) {
        float cc = cf[gc];
        float4 v = g4[bOff + (size_t)(half * 32 + gc) * SPATIAL4 + base4];
        acc.x += v.x * cc; acc.y += v.y * cc;
        acc.z += v.z * cc; acc.w += v.w * cc;
    }
    __shared__ float4 red[128];
    if (half == 1) red[pos] = acc;
    __syncthreads();
    if (half == 0) {
        float4 o = red[pos];
        float d = coef[128];
        float4 s;
        s.x = 1.f / (1.f + expf(-(acc.x + o.x + d)));
        s.y = 1.f / (1.f + expf(-(acc.y + o.y + d)));
        s.z = 1.f / (1.f + expf(-(acc.z + o.z + d)));
        s.w = 1.f / (1.f + expf(-(acc.w + o.w + d)));
        red[pos] = s;
    }
    __syncthreads();
    float4 s = red[pos];
    #pragma unroll 8
    for (int l = 0; l < 32; ++l) {
        size_t idx = bOff + (size_t)(half * 32 + l) * SPATIAL4 + base4;
        float4 xv = x4[idx];
        o4[idx] = make_float4(xv.x * s.x, xv.y * s.y, xv.z * s.z, xv.w * s.w);
    }
}

extern "C" void kernel_launch(void* const* d_in, const int* in_sizes, int n_in,
                              void* d_out, int out_size, void* d_ws, size_t ws_size,
                              hipStream_t stream) {
    const float* g        = (const float*)d_in[0];
    const float* x        = (const float*)d_in[1];
    const float* w1       = (const float*)d_in[2];
    const float* b1       = (const float*)d_in[3];
    const float* w2       = (const float*)d_in[4];
    const float* b2       = (const float*)d_in[5];
    const float* psi_w    = (const float*)d_in[6];
    const float* psi_b    = (const float*)d_in[7];
    const float* bn_gamma = (const float*)d_in[8];
    const float* bn_beta  = (const float*)d_in[9];
    const float* bn_mean  = (const float*)d_in[10];
    const float* bn_var   = (const float*)d_in[11];
    float* out = (float*)d_out;
    float* ws  = (float*)d_ws;

    float* partial = ws;         // 1024 floats
    float* coef    = ws + 1024;  // 129 floats

    mean_kernel<<<1024, 256, 0, stream>>>(g, x, partial);
    mlp_kernel<<<128, 64, 0, stream>>>(partial, w1, b1, w2, b2, psi_w, psi_b,
                                       bn_gamma, bn_beta, bn_mean, bn_var, coef);
    apply_kernel<<<1024, 256, 0, stream>>>(g, x, coef, out);
}